// Round 1
// baseline (305.519 us; speedup 1.0000x reference)
//
#include <hip/hip_runtime.h>

#define N_NODES 50000
#define N_EDGES 800000
#define NREL 8
#define NB8 (N_NODES * NREL)      // 400000
#define SCAN_T 12500              // NB8 / 32
#define KSTEPS 36                 // 1152 / 32
#define A_STRIDE 1160             // shorts per LDS row
#define NT32 1563                 // ceil(N_NODES / 32)

typedef __attribute__((ext_vector_type(8))) short short8;
typedef __attribute__((ext_vector_type(4))) float f32x4;
typedef __attribute__((ext_vector_type(2))) float f32x2;

__device__ __forceinline__ unsigned short f2bf(float v) {
    union { float f; unsigned int u; } c; c.f = v;
    return (unsigned short)((c.u + 0x7FFFu + ((c.u >> 16) & 1u)) >> 16);
}
__device__ __forceinline__ float bfhi2f(unsigned int u) {
    union { unsigned int u; float f; } c; c.u = u & 0xFFFF0000u; return c.f;
}
__device__ __forceinline__ float bflo2f(unsigned int u) {
    union { unsigned int u; float f; } c; c.u = u << 16; return c.f;
}

// ---------------------------------------------------------------------------
// Fused prep: zero cnt + cast X to bf16 + pack 3 weight sets
// ---------------------------------------------------------------------------
#define PREP_Z   (NB8 / 4)
#define PREP_X   (N_NODES * 32)
#define PREP_P   (8 * KSTEPS * 64)
#define PREP_P2  (1 * KSTEPS * 64)
#define PREP_TOTAL (PREP_Z + PREP_X + 2 * PREP_P + PREP_P2)

__device__ __forceinline__ void pack_one(int idx, const float* __restrict__ root,
                                         const float* __restrict__ W,
                                         unsigned short* __restrict__ Wpack, int FOUT) {
    int lane = idx & 63;
    int ks = (idx >> 6) % KSTEPS;
    int ct = idx / (KSTEPS * 64);
    int kbase = ks * 32 + (lane >> 4) * 8;
    int col = ct * 16 + (lane & 15);
    union { unsigned short us[8]; uint4 v; } u;
#pragma unroll
    for (int j = 0; j < 8; j++) {
        int k = kbase + j;
        float val = (k < 128) ? root[(size_t)k * FOUT + col]
                              : W[(size_t)(k - 128) * FOUT + col];
        u.us[j] = f2bf(val);
    }
    ((uint4*)Wpack)[idx] = u.v;
}

__global__ void prep_kernel(const float* __restrict__ X, unsigned int* __restrict__ Xb2,
                            const float* __restrict__ r0, const float* __restrict__ w0,
                            unsigned short* __restrict__ Wp0,
                            const float* __restrict__ r1, const float* __restrict__ w1,
                            unsigned short* __restrict__ Wp1,
                            const float* __restrict__ r2, const float* __restrict__ w2,
                            unsigned short* __restrict__ Wp2,
                            int* __restrict__ cnt) {
    int t = blockIdx.x * blockDim.x + threadIdx.x;
    if (t < PREP_Z) { ((int4*)cnt)[t] = make_int4(0, 0, 0, 0); return; }
    t -= PREP_Z;
    if (t < PREP_X) {
        float4 v = ((const float4*)X)[t];
        unsigned int p0 = (unsigned int)f2bf(v.x) | ((unsigned int)f2bf(v.y) << 16);
        unsigned int p1 = (unsigned int)f2bf(v.z) | ((unsigned int)f2bf(v.w) << 16);
        ((uint2*)Xb2)[t] = make_uint2(p0, p1);
        return;
    }
    t -= PREP_X;
    if (t < PREP_P) { pack_one(t, r0, w0, Wp0, 128); return; }
    t -= PREP_P;
    if (t < PREP_P) { pack_one(t, r1, w1, Wp1, 128); return; }
    t -= PREP_P;
    if (t < PREP_P2) pack_one(t, r2, w2, Wp2, 16);
}

// ---------------------------------------------------------------------------
// CSR build, rank-based: ONE atomic pass (rank), scan, then plain placement.
// ---------------------------------------------------------------------------
__global__ void rank_kernel(const int* __restrict__ ei, const int* __restrict__ et,
                            int* __restrict__ cnt, int* __restrict__ rank, int E) {
    int e = blockIdx.x * blockDim.x + threadIdx.x;
    if (e >= E) return;
    int d = ei[E + e];
    int t = et[e];
    rank[e] = atomicAdd(&cnt[d * NREL + t], 1);
}

__global__ void scanA_kernel(const int* __restrict__ cnt, int* __restrict__ tsum) {
    int g = blockIdx.x * blockDim.x + threadIdx.x;
    if (g >= SCAN_T) return;
    const int4* p = (const int4*)(cnt + (size_t)g * 32);
    int s = 0;
#pragma unroll
    for (int j = 0; j < 8; j++) {
        int4 v = p[j];
        s += v.x + v.y + v.z + v.w;
    }
    tsum[g] = s;
}

__global__ void scanB_kernel(const int* __restrict__ tsum, int* __restrict__ toff) {
    __shared__ int part[1024];
    int t = threadIdx.x;
    const int C = 13;
    int n0 = t * C, n1 = n0 + C; if (n1 > SCAN_T) n1 = SCAN_T;
    int s = 0;
    for (int n = n0; n < n1; n++) s += tsum[n];
    part[t] = s;
    __syncthreads();
    for (int off = 1; off < 1024; off <<= 1) {
        int v = (t >= off) ? part[t - off] : 0;
        __syncthreads();
        part[t] += v;
        __syncthreads();
    }
    int run = (t > 0) ? part[t - 1] : 0;
    for (int n = n0; n < n1; n++) { toff[n] = run; run += tsum[n]; }
}

__global__ void scanC_kernel(const int* __restrict__ cnt, const int* __restrict__ toff,
                             int* __restrict__ rs8) {
    int g = blockIdx.x * blockDim.x + threadIdx.x;
    if (g >= SCAN_T) return;
    int run = toff[g];
    int base = g * 32;
#pragma unroll 4
    for (int j = 0; j < 32; j++) {
        rs8[base + j] = run;
        run += cnt[base + j];
    }
    if (g == 0) rs8[NB8] = N_EDGES;
}

__global__ void place_kernel(const int* __restrict__ ei, const int* __restrict__ et,
                             const int* __restrict__ rank, const int* __restrict__ rs8,
                             unsigned short* __restrict__ csr_src, int E) {
    int e = blockIdx.x * blockDim.x + threadIdx.x;
    if (e >= E) return;
    int s = ei[e];
    int d = ei[E + e];
    int t = et[e];
    csr_src[rs8[d * NREL + t] + rank[e]] = (unsigned short)s;
}

// ---------------------------------------------------------------------------
// Fused layer, M-tile = 32 nodes / block (1024 threads, 16 waves).
// Phase A: identical per-wave structure to the verified M=16 version (wave
// owns 2 dst nodes, contiguous edge stream, 16 flush boundaries); 16 waves
// cover 32 nodes. 2 blocks/CU (LDS 74 KiB) keeps 32 waves/CU occupancy.
// Phase B: K split in half across wave pairs (kh = wave>>3) so each Wpack
// b-fragment is loaded ONCE per block and feeds TWO MFMAs (row-groups 0-15
// and 16-31) -> global B traffic per node halves vs M=16. Wave pairs then
// reduce their K-half partials through a 16 KiB LDS region.
// ---------------------------------------------------------------------------
template <int FOUT, bool RELU>
__global__ __launch_bounds__(1024, 8) void layer_kernel(
    const unsigned int* __restrict__ Xb2,        // [N][64] bf16 dword pairs
    const int* __restrict__ rs8,                 // [NB8+1]
    const unsigned short* __restrict__ csr_src,  // [E] src ids sorted by (dst,rel)
    const unsigned short* __restrict__ Wpack,    // [NCT][36][64][8]
    const float* __restrict__ bias,
    void* __restrict__ Yout)
{
    __shared__ __align__(16) unsigned short Abuf[32][A_STRIDE];

    int tid = threadIdx.x;
    int wave = tid >> 6, lane = tid & 63;
    int l15 = lane & 15;
    int node0 = blockIdx.x * 32;

    // ---------------- Phase A
    int gn0 = node0 + wave * 2;
    if (gn0 < N_NODES) {
        unsigned int* row0 = (unsigned int*)&Abuf[wave * 2][0];
        unsigned int* row1 = (unsigned int*)&Abuf[wave * 2 + 1][0];

        int bl = lane <= 16 ? lane : 16;
        int bv = rs8[gn0 * 8 + bl];                 // lanes 0..16: 16 segment bounds
        unsigned int self0 = Xb2[(size_t)gn0 * 64 + lane];
        unsigned int self1 = Xb2[(size_t)(gn0 + 1) * 64 + lane];

        int e     = __builtin_amdgcn_readlane(bv, 0);
        int e_end = __builtin_amdgcn_readlane(bv, 16);

        row0[lane] = self0;
        row1[lane] = self1;

        int r = 0;                                   // segment index 0..15
        int segs = e;
        int be = __builtin_amdgcn_readlane(bv, 1);
        f32x2 av = (f32x2){0.f, 0.f};

#define FLUSH_R()                                                              \
        do {                                                                   \
            int c_ = be - segs;                                                \
            float iv_ = 1.0f / (float)(c_ > 0 ? c_ : 1);                       \
            unsigned int pk_ = (unsigned int)f2bf(av.x * iv_)                  \
                             | ((unsigned int)f2bf(av.y * iv_) << 16);         \
            unsigned int* rw_ = (r < 8) ? row0 : row1;                         \
            rw_[(1 + (r & 7)) * 64 + lane] = pk_;                              \
            av = (f32x2){0.f, 0.f}; segs = be; r++;                            \
            be = __builtin_amdgcn_readlane(bv, r + 1 <= 16 ? r + 1 : 16);      \
        } while (0)

        if (e < e_end) {
            int e1m = e_end - 1;
            int ma = e + l15; if (ma > e1m) ma = e1m;
            unsigned int mv = csr_src[ma];            // lanes 0-15: metas e..e+15
            while (e < e_end) {
                int bn = e_end - e; if (bn > 16) bn = 16;
                int sc[16];
#pragma unroll
                for (int k = 0; k < 16; k++) sc[k] = __builtin_amdgcn_readlane((int)mv, k);
                unsigned int xp[16];
#pragma unroll
                for (int k = 0; k < 16; k++) xp[k] = Xb2[(size_t)sc[k] * 64 + lane];
                int en = e + bn;
                if (en < e_end) {                     // prefetch next meta window
                    int mb = en + l15; if (mb > e1m) mb = e1m;
                    mv = csr_src[mb];
                }
#pragma unroll
                for (int k = 0; k < 16; k++) {
                    if (k < bn) {                     // bn is wave-uniform
                        int ec = e + k;
                        while (ec >= be) FLUSH_R();
                        av += (f32x2){bflo2f(xp[k]), bfhi2f(xp[k])};
                    }
                }
                e = en;
            }
        }
        while (r < 16) FLUSH_R();
#undef FLUSH_R
    }
    __syncthreads();

    // ---------------- Phase B
    int quad = lane >> 4, l16 = lane & 15;
    if constexpr (FOUT == 128) {
        int ct = wave & 7, kh = wave >> 3;           // kh: which K-half
        f32x4 acc0 = (f32x4){0.f, 0.f, 0.f, 0.f};    // rows 0-15
        f32x4 acc1 = (f32x4){0.f, 0.f, 0.f, 0.f};    // rows 16-31
        int ks0 = kh * 18;
        for (int ks = ks0; ks < ks0 + 18; ks++) {
            short8 b = *(const short8*)(Wpack + (((size_t)ct * KSTEPS + ks) * 64 + lane) * 8);
            short8 a0 = *(const short8*)&Abuf[l16][ks * 32 + quad * 8];
            short8 a1 = *(const short8*)&Abuf[16 + l16][ks * 32 + quad * 8];
            acc0 = __builtin_amdgcn_mfma_f32_16x16x32_bf16(a0, b, acc0, 0, 0, 0);
            acc1 = __builtin_amdgcn_mfma_f32_16x16x32_bf16(a1, b, acc1, 0, 0, 0);
        }
        __syncthreads();                              // Abuf A-data fully consumed
        f32x4* rv = (f32x4*)&Abuf[0][0];              // 16 KiB reduce region
        if (wave >= 8) {
            rv[((wave - 8) * 64 + lane) * 2]     = acc0;
            rv[((wave - 8) * 64 + lane) * 2 + 1] = acc1;
        }
        __syncthreads();
        if (wave < 8) {
            f32x4 s0 = acc0 + rv[(wave * 64 + lane) * 2];
            f32x4 s1 = acc1 + rv[(wave * 64 + lane) * 2 + 1];
            unsigned short* Yb = (unsigned short*)Yout;
            int h = ct * 16 + l16;
            float bvs = bias[h];
#pragma unroll
            for (int r4 = 0; r4 < 4; r4++) {
                int n0r = node0 + quad * 4 + r4;      // rows 0-15: always < N
                float v0 = s0[r4] + bvs;
                if (RELU) v0 = v0 > 0.f ? v0 : 0.f;
                Yb[(size_t)n0r * 128 + h] = f2bf(v0);
                int n1r = node0 + 16 + quad * 4 + r4; // rows 16-31: guard tail
                float v1 = s1[r4] + bvs;
                if (RELU) v1 = v1 > 0.f ? v1 : 0.f;
                if (n1r < N_NODES) Yb[(size_t)n1r * 128 + h] = f2bf(v1);
            }
        }
    } else {
        // FOUT == 16: ct=0 only; 16-way K-split (waves 0-3: 3 ks, 4-15: 2 ks)
        int ks0 = (wave < 4) ? wave * 3 : 12 + (wave - 4) * 2;
        int ksn = (wave < 4) ? 3 : 2;
        f32x4 acc0 = (f32x4){0.f, 0.f, 0.f, 0.f};
        f32x4 acc1 = (f32x4){0.f, 0.f, 0.f, 0.f};
        for (int ks = ks0; ks < ks0 + ksn; ks++) {
            short8 b = *(const short8*)(Wpack + ((size_t)ks * 64 + lane) * 8);
            short8 a0 = *(const short8*)&Abuf[l16][ks * 32 + quad * 8];
            short8 a1 = *(const short8*)&Abuf[16 + l16][ks * 32 + quad * 8];
            acc0 = __builtin_amdgcn_mfma_f32_16x16x32_bf16(a0, b, acc0, 0, 0, 0);
            acc1 = __builtin_amdgcn_mfma_f32_16x16x32_bf16(a1, b, acc1, 0, 0, 0);
        }
        __syncthreads();
        float* red = (float*)&Abuf[0][0];             // [16][64][8] = 32 KiB
        f32x4* rv = (f32x4*)red;
        rv[(wave * 64 + lane) * 2]     = acc0;
        rv[(wave * 64 + lane) * 2 + 1] = acc1;
        __syncthreads();
        if (tid < 512) {
            int nr = tid >> 4, h = tid & 15;          // nr 0..31, h 0..15
            int g = nr >> 4, rem = nr & 15;
            int q_ = rem >> 2, r4 = rem & 3;
            int lsrc = q_ * 16 + h;
            float s = 0.f;
#pragma unroll
            for (int w2 = 0; w2 < 16; w2++)
                s += red[(w2 * 64 + lsrc) * 8 + g * 4 + r4];
            int node = node0 + nr;
            float v = s + bias[h];
            if (RELU) v = v > 0.f ? v : 0.f;
            if (node < N_NODES)
                ((float*)Yout)[(size_t)node * 16 + h] = v;
        }
    }
}

// ---------------------------------------------------------------------------
extern "C" void kernel_launch(void* const* d_in, const int* in_sizes, int n_in,
                              void* d_out, int out_size, void* d_ws, size_t ws_size,
                              hipStream_t stream) {
    const float* x  = (const float*)d_in[0];
    const int*   ei = (const int*)d_in[1];
    const int*   et = (const int*)d_in[2];
    const float* w0 = (const float*)d_in[3];
    const float* r0 = (const float*)d_in[4];
    const float* b0 = (const float*)d_in[5];
    const float* w1 = (const float*)d_in[6];
    const float* r1 = (const float*)d_in[7];
    const float* b1 = (const float*)d_in[8];
    const float* w2 = (const float*)d_in[9];
    const float* r2 = (const float*)d_in[10];
    const float* b2 = (const float*)d_in[11];

    char* wsp = (char*)d_ws;
    size_t off = 0;
    auto alloc = [&](size_t bytes) -> void* {
        void* p = wsp + off;
        off += (bytes + 255) & ~(size_t)255;
        return p;
    };

    int* cnt    = (int*)alloc((size_t)NB8 * 4);
    int* rs8    = (int*)alloc(((size_t)NB8 + 1) * 4);
    int* rank   = (int*)alloc((size_t)N_EDGES * 4);
    int* tsum   = (int*)alloc((size_t)SCAN_T * 4);
    int* toff   = (int*)alloc((size_t)SCAN_T * 4);
    unsigned short* csr_src = (unsigned short*)alloc((size_t)N_EDGES * 2);
    unsigned short* Wp0 = (unsigned short*)alloc((size_t)8 * KSTEPS * 64 * 8 * 2);
    unsigned short* Wp1 = (unsigned short*)alloc((size_t)8 * KSTEPS * 64 * 8 * 2);
    unsigned short* Wp2 = (unsigned short*)alloc((size_t)1 * KSTEPS * 64 * 8 * 2);
    unsigned int* Xb = (unsigned int*)alloc((size_t)N_NODES * 64 * 4);
    unsigned int* H0 = (unsigned int*)alloc((size_t)N_NODES * 64 * 4);
    unsigned int* H1 = (unsigned int*)alloc((size_t)N_NODES * 64 * 4);

    prep_kernel<<<dim3((PREP_TOTAL + 255) / 256), dim3(256), 0, stream>>>(
        x, Xb, r0, w0, Wp0, r1, w1, Wp1, r2, w2, Wp2, cnt);
    rank_kernel<<<dim3((N_EDGES + 255) / 256), dim3(256), 0, stream>>>(ei, et, cnt, rank, N_EDGES);
    scanA_kernel<<<dim3((SCAN_T + 255) / 256), dim3(256), 0, stream>>>(cnt, tsum);
    scanB_kernel<<<dim3(1), dim3(1024), 0, stream>>>(tsum, toff);
    scanC_kernel<<<dim3((SCAN_T + 255) / 256), dim3(256), 0, stream>>>(cnt, toff, rs8);
    place_kernel<<<dim3((N_EDGES + 255) / 256), dim3(256), 0, stream>>>(ei, et, rank, rs8,
                                                                        csr_src, N_EDGES);

    layer_kernel<128, true ><<<dim3(NT32), dim3(1024), 0, stream>>>(
        Xb, rs8, csr_src, Wp0, b0, (void*)H0);
    layer_kernel<128, true ><<<dim3(NT32), dim3(1024), 0, stream>>>(
        H0, rs8, csr_src, Wp1, b1, (void*)H1);
    layer_kernel<16, false><<<dim3(NT32), dim3(1024), 0, stream>>>(
        H1, rs8, csr_src, Wp2, b2, d_out);
}

// Round 2
// 291.106 us; speedup vs baseline: 1.0495x; 1.0495x over previous
//
#include <hip/hip_runtime.h>

#define N_NODES 50000
#define N_EDGES 800000
#define NREL 8
#define NB8 (N_NODES * NREL)      // 400000
#define SCAN_T 12500              // NB8 / 32
#define KSTEPS 36                 // 1152 / 32
#define A_STRIDE 1160             // shorts per LDS row
#define NT32 1563                 // ceil(N_NODES / 32)

typedef __attribute__((ext_vector_type(8))) short short8;
typedef __attribute__((ext_vector_type(4))) float f32x4;
typedef __attribute__((ext_vector_type(2))) float f32x2;

__device__ __forceinline__ unsigned short f2bf(float v) {
    union { float f; unsigned int u; } c; c.f = v;
    return (unsigned short)((c.u + 0x7FFFu + ((c.u >> 16) & 1u)) >> 16);
}
__device__ __forceinline__ float bfhi2f(unsigned int u) {
    union { unsigned int u; float f; } c; c.u = u & 0xFFFF0000u; return c.f;
}
__device__ __forceinline__ float bflo2f(unsigned int u) {
    union { unsigned int u; float f; } c; c.u = u << 16; return c.f;
}

// ---------------------------------------------------------------------------
// Fused prep: zero cnt + cast X to bf16 + pack 3 weight sets
// ---------------------------------------------------------------------------
#define PREP_Z   (NB8 / 4)
#define PREP_X   (N_NODES * 32)
#define PREP_P   (8 * KSTEPS * 64)
#define PREP_P2  (1 * KSTEPS * 64)
#define PREP_TOTAL (PREP_Z + PREP_X + 2 * PREP_P + PREP_P2)

__device__ __forceinline__ void pack_one(int idx, const float* __restrict__ root,
                                         const float* __restrict__ W,
                                         unsigned short* __restrict__ Wpack, int FOUT) {
    int lane = idx & 63;
    int ks = (idx >> 6) % KSTEPS;
    int ct = idx / (KSTEPS * 64);
    int kbase = ks * 32 + (lane >> 4) * 8;
    int col = ct * 16 + (lane & 15);
    union { unsigned short us[8]; uint4 v; } u;
#pragma unroll
    for (int j = 0; j < 8; j++) {
        int k = kbase + j;
        float val = (k < 128) ? root[(size_t)k * FOUT + col]
                              : W[(size_t)(k - 128) * FOUT + col];
        u.us[j] = f2bf(val);
    }
    ((uint4*)Wpack)[idx] = u.v;
}

__global__ void prep_kernel(const float* __restrict__ X, unsigned int* __restrict__ Xb2,
                            const float* __restrict__ r0, const float* __restrict__ w0,
                            unsigned short* __restrict__ Wp0,
                            const float* __restrict__ r1, const float* __restrict__ w1,
                            unsigned short* __restrict__ Wp1,
                            const float* __restrict__ r2, const float* __restrict__ w2,
                            unsigned short* __restrict__ Wp2,
                            int* __restrict__ cnt) {
    int t = blockIdx.x * blockDim.x + threadIdx.x;
    if (t < PREP_Z) { ((int4*)cnt)[t] = make_int4(0, 0, 0, 0); return; }
    t -= PREP_Z;
    if (t < PREP_X) {
        float4 v = ((const float4*)X)[t];
        unsigned int p0 = (unsigned int)f2bf(v.x) | ((unsigned int)f2bf(v.y) << 16);
        unsigned int p1 = (unsigned int)f2bf(v.z) | ((unsigned int)f2bf(v.w) << 16);
        ((uint2*)Xb2)[t] = make_uint2(p0, p1);
        return;
    }
    t -= PREP_X;
    if (t < PREP_P) { pack_one(t, r0, w0, Wp0, 128); return; }
    t -= PREP_P;
    if (t < PREP_P) { pack_one(t, r1, w1, Wp1, 128); return; }
    t -= PREP_P;
    if (t < PREP_P2) pack_one(t, r2, w2, Wp2, 16);
}

// ---------------------------------------------------------------------------
// CSR build, rank-based: ONE atomic pass (rank), scan, then plain placement.
// ---------------------------------------------------------------------------
__global__ void rank_kernel(const int* __restrict__ ei, const int* __restrict__ et,
                            int* __restrict__ cnt, int* __restrict__ rank, int E) {
    int e = blockIdx.x * blockDim.x + threadIdx.x;
    if (e >= E) return;
    int d = ei[E + e];
    int t = et[e];
    rank[e] = atomicAdd(&cnt[d * NREL + t], 1);
}

__global__ void scanA_kernel(const int* __restrict__ cnt, int* __restrict__ tsum) {
    int g = blockIdx.x * blockDim.x + threadIdx.x;
    if (g >= SCAN_T) return;
    const int4* p = (const int4*)(cnt + (size_t)g * 32);
    int s = 0;
#pragma unroll
    for (int j = 0; j < 8; j++) {
        int4 v = p[j];
        s += v.x + v.y + v.z + v.w;
    }
    tsum[g] = s;
}

__global__ void scanB_kernel(const int* __restrict__ tsum, int* __restrict__ toff) {
    __shared__ int part[1024];
    int t = threadIdx.x;
    const int C = 13;
    int n0 = t * C, n1 = n0 + C; if (n1 > SCAN_T) n1 = SCAN_T;
    int s = 0;
    for (int n = n0; n < n1; n++) s += tsum[n];
    part[t] = s;
    __syncthreads();
    for (int off = 1; off < 1024; off <<= 1) {
        int v = (t >= off) ? part[t - off] : 0;
        __syncthreads();
        part[t] += v;
        __syncthreads();
    }
    int run = (t > 0) ? part[t - 1] : 0;
    for (int n = n0; n < n1; n++) { toff[n] = run; run += tsum[n]; }
}

__global__ void scanC_kernel(const int* __restrict__ cnt, const int* __restrict__ toff,
                             int* __restrict__ rs8) {
    int g = blockIdx.x * blockDim.x + threadIdx.x;
    if (g >= SCAN_T) return;
    int run = toff[g];
    int base = g * 32;
#pragma unroll 4
    for (int j = 0; j < 32; j++) {
        rs8[base + j] = run;
        run += cnt[base + j];
    }
    if (g == 0) rs8[NB8] = N_EDGES;
}

__global__ void place_kernel(const int* __restrict__ ei, const int* __restrict__ et,
                             const int* __restrict__ rank, const int* __restrict__ rs8,
                             unsigned short* __restrict__ csr_src, int E) {
    int e = blockIdx.x * blockDim.x + threadIdx.x;
    if (e >= E) return;
    int s = ei[e];
    int d = ei[E + e];
    int t = et[e];
    csr_src[rs8[d * NREL + t] + rank[e]] = (unsigned short)s;
}

// ---------------------------------------------------------------------------
// Fused layer, M-tile = 32 nodes / block (1024 threads, 16 waves).
// R2 changes vs R1 (counter-driven: VALUBusy 53%, LDS_BANK_CONFLICT 3.9M):
//  * FLUSH: precise-IEEE divide (~12 VALU) -> v_rcp_f32 (1); 2x software
//    f2bf (~10 VALU) -> one v_cvt_pk_bf16_f32. ~28 -> ~7 instrs per flush,
//    16 flushes per wave = the dominant Phase-A VALU term removed.
//  * Reduce regions: f32x4 slot stride 32B put 16 lanes on one start bank
//    (b128 16-way conflict). XOR-swizzle slot ^ (lane&7): start banks
//    {0,12,24,20,16,28,8,4} per 8 lanes -> conflict-free (2-way is free).
// ---------------------------------------------------------------------------
template <int FOUT, bool RELU>
__global__ __launch_bounds__(1024, 8) void layer_kernel(
    const unsigned int* __restrict__ Xb2,        // [N][64] bf16 dword pairs
    const int* __restrict__ rs8,                 // [NB8+1]
    const unsigned short* __restrict__ csr_src,  // [E] src ids sorted by (dst,rel)
    const unsigned short* __restrict__ Wpack,    // [NCT][36][64][8]
    const float* __restrict__ bias,
    void* __restrict__ Yout)
{
    __shared__ __align__(16) unsigned short Abuf[32][A_STRIDE];

    int tid = threadIdx.x;
    int wave = tid >> 6, lane = tid & 63;
    int l15 = lane & 15;
    int node0 = blockIdx.x * 32;

    // ---------------- Phase A
    int gn0 = node0 + wave * 2;
    if (gn0 < N_NODES) {
        unsigned int* row0 = (unsigned int*)&Abuf[wave * 2][0];
        unsigned int* row1 = (unsigned int*)&Abuf[wave * 2 + 1][0];

        int bl = lane <= 16 ? lane : 16;
        int bv = rs8[gn0 * 8 + bl];                 // lanes 0..16: 16 segment bounds
        unsigned int self0 = Xb2[(size_t)gn0 * 64 + lane];
        unsigned int self1 = Xb2[(size_t)(gn0 + 1) * 64 + lane];

        int e     = __builtin_amdgcn_readlane(bv, 0);
        int e_end = __builtin_amdgcn_readlane(bv, 16);

        row0[lane] = self0;
        row1[lane] = self1;

        int r = 0;                                   // segment index 0..15
        int segs = e;
        int be = __builtin_amdgcn_readlane(bv, 1);
        f32x2 av = (f32x2){0.f, 0.f};

#define FLUSH_R()                                                              \
        do {                                                                   \
            int c_ = be - segs;                                                \
            float iv_ = __builtin_amdgcn_rcpf((float)(c_ > 0 ? c_ : 1));       \
            unsigned int pk_;                                                  \
            asm("v_cvt_pk_bf16_f32 %0, %1, %2"                                 \
                : "=v"(pk_) : "v"(av.x * iv_), "v"(av.y * iv_));               \
            unsigned int* rw_ = (r < 8) ? row0 : row1;                         \
            rw_[(1 + (r & 7)) * 64 + lane] = pk_;                              \
            av = (f32x2){0.f, 0.f}; segs = be; r++;                            \
            be = __builtin_amdgcn_readlane(bv, r + 1 <= 16 ? r + 1 : 16);      \
        } while (0)

        if (e < e_end) {
            int e1m = e_end - 1;
            int ma = e + l15; if (ma > e1m) ma = e1m;
            unsigned int mv = csr_src[ma];            // lanes 0-15: metas e..e+15
            while (e < e_end) {
                int bn = e_end - e; if (bn > 16) bn = 16;
                int sc[16];
#pragma unroll
                for (int k = 0; k < 16; k++) sc[k] = __builtin_amdgcn_readlane((int)mv, k);
                unsigned int xp[16];
#pragma unroll
                for (int k = 0; k < 16; k++) xp[k] = Xb2[(size_t)sc[k] * 64 + lane];
                int en = e + bn;
                if (en < e_end) {                     // prefetch next meta window
                    int mb = en + l15; if (mb > e1m) mb = e1m;
                    mv = csr_src[mb];
                }
#pragma unroll
                for (int k = 0; k < 16; k++) {
                    if (k < bn) {                     // bn is wave-uniform
                        int ec = e + k;
                        while (ec >= be) FLUSH_R();
                        av += (f32x2){bflo2f(xp[k]), bfhi2f(xp[k])};
                    }
                }
                e = en;
            }
        }
        while (r < 16) FLUSH_R();
#undef FLUSH_R
    }
    __syncthreads();

    // ---------------- Phase B
    int quad = lane >> 4, l16 = lane & 15;
    int swz = lane & 7;                               // reduce-region XOR key
    if constexpr (FOUT == 128) {
        int ct = wave & 7, kh = wave >> 3;           // kh: which K-half
        f32x4 acc0 = (f32x4){0.f, 0.f, 0.f, 0.f};    // rows 0-15
        f32x4 acc1 = (f32x4){0.f, 0.f, 0.f, 0.f};    // rows 16-31
        int ks0 = kh * 18;
        for (int ks = ks0; ks < ks0 + 18; ks++) {
            short8 b = *(const short8*)(Wpack + (((size_t)ct * KSTEPS + ks) * 64 + lane) * 8);
            short8 a0 = *(const short8*)&Abuf[l16][ks * 32 + quad * 8];
            short8 a1 = *(const short8*)&Abuf[16 + l16][ks * 32 + quad * 8];
            acc0 = __builtin_amdgcn_mfma_f32_16x16x32_bf16(a0, b, acc0, 0, 0, 0);
            acc1 = __builtin_amdgcn_mfma_f32_16x16x32_bf16(a1, b, acc1, 0, 0, 0);
        }
        __syncthreads();                              // Abuf A-data fully consumed
        f32x4* rv = (f32x4*)&Abuf[0][0];              // 16 KiB reduce region
        if (wave >= 8) {
            int sb = ((wave - 8) * 64 + lane) * 2;
            rv[sb ^ swz]       = acc0;
            rv[(sb + 1) ^ swz] = acc1;
        }
        __syncthreads();
        if (wave < 8) {
            int sb = (wave * 64 + lane) * 2;
            f32x4 s0 = acc0 + rv[sb ^ swz];
            f32x4 s1 = acc1 + rv[(sb + 1) ^ swz];
            unsigned short* Yb = (unsigned short*)Yout;
            int h = ct * 16 + l16;
            float bvs = bias[h];
#pragma unroll
            for (int r4 = 0; r4 < 4; r4++) {
                int n0r = node0 + quad * 4 + r4;      // rows 0-15: always < N
                float v0 = s0[r4] + bvs;
                if (RELU) v0 = v0 > 0.f ? v0 : 0.f;
                Yb[(size_t)n0r * 128 + h] = f2bf(v0);
                int n1r = node0 + 16 + quad * 4 + r4; // rows 16-31: guard tail
                float v1 = s1[r4] + bvs;
                if (RELU) v1 = v1 > 0.f ? v1 : 0.f;
                if (n1r < N_NODES) Yb[(size_t)n1r * 128 + h] = f2bf(v1);
            }
        }
    } else {
        // FOUT == 16: ct=0 only; 16-way K-split (waves 0-3: 3 ks, 4-15: 2 ks)
        int ks0 = (wave < 4) ? wave * 3 : 12 + (wave - 4) * 2;
        int ksn = (wave < 4) ? 3 : 2;
        f32x4 acc0 = (f32x4){0.f, 0.f, 0.f, 0.f};
        f32x4 acc1 = (f32x4){0.f, 0.f, 0.f, 0.f};
        for (int ks = ks0; ks < ks0 + ksn; ks++) {
            short8 b = *(const short8*)(Wpack + ((size_t)ks * 64 + lane) * 8);
            short8 a0 = *(const short8*)&Abuf[l16][ks * 32 + quad * 8];
            short8 a1 = *(const short8*)&Abuf[16 + l16][ks * 32 + quad * 8];
            acc0 = __builtin_amdgcn_mfma_f32_16x16x32_bf16(a0, b, acc0, 0, 0, 0);
            acc1 = __builtin_amdgcn_mfma_f32_16x16x32_bf16(a1, b, acc1, 0, 0, 0);
        }
        __syncthreads();
        float* red = (float*)&Abuf[0][0];             // [16][64][2] f32x4 = 32 KiB
        f32x4* rv = (f32x4*)red;
        int sb = (wave * 64 + lane) * 2;
        rv[sb ^ swz]       = acc0;
        rv[(sb + 1) ^ swz] = acc1;
        __syncthreads();
        if (tid < 512) {
            int nr = tid >> 4, h = tid & 15;          // nr 0..31, h 0..15
            int g = nr >> 4, rem = nr & 15;
            int q_ = rem >> 2, r4 = rem & 3;
            int lsrc = q_ * 16 + h;
            float s = 0.f;
#pragma unroll
            for (int w2 = 0; w2 < 16; w2++) {
                int sl = ((w2 * 64 + lsrc) * 2 + g) ^ (lsrc & 7);
                s += red[sl * 4 + r4];
            }
            int node = node0 + nr;
            float v = s + bias[h];
            if (RELU) v = v > 0.f ? v : 0.f;
            if (node < N_NODES)
                ((float*)Yout)[(size_t)node * 16 + h] = v;
        }
    }
}

// ---------------------------------------------------------------------------
extern "C" void kernel_launch(void* const* d_in, const int* in_sizes, int n_in,
                              void* d_out, int out_size, void* d_ws, size_t ws_size,
                              hipStream_t stream) {
    const float* x  = (const float*)d_in[0];
    const int*   ei = (const int*)d_in[1];
    const int*   et = (const int*)d_in[2];
    const float* w0 = (const float*)d_in[3];
    const float* r0 = (const float*)d_in[4];
    const float* b0 = (const float*)d_in[5];
    const float* w1 = (const float*)d_in[6];
    const float* r1 = (const float*)d_in[7];
    const float* b1 = (const float*)d_in[8];
    const float* w2 = (const float*)d_in[9];
    const float* r2 = (const float*)d_in[10];
    const float* b2 = (const float*)d_in[11];

    char* wsp = (char*)d_ws;
    size_t off = 0;
    auto alloc = [&](size_t bytes) -> void* {
        void* p = wsp + off;
        off += (bytes + 255) & ~(size_t)255;
        return p;
    };

    int* cnt    = (int*)alloc((size_t)NB8 * 4);
    int* rs8    = (int*)alloc(((size_t)NB8 + 1) * 4);
    int* rank   = (int*)alloc((size_t)N_EDGES * 4);
    int* tsum   = (int*)alloc((size_t)SCAN_T * 4);
    int* toff   = (int*)alloc((size_t)SCAN_T * 4);
    unsigned short* csr_src = (unsigned short*)alloc((size_t)N_EDGES * 2);
    unsigned short* Wp0 = (unsigned short*)alloc((size_t)8 * KSTEPS * 64 * 8 * 2);
    unsigned short* Wp1 = (unsigned short*)alloc((size_t)8 * KSTEPS * 64 * 8 * 2);
    unsigned short* Wp2 = (unsigned short*)alloc((size_t)1 * KSTEPS * 64 * 8 * 2);
    unsigned int* Xb = (unsigned int*)alloc((size_t)N_NODES * 64 * 4);
    unsigned int* H0 = (unsigned int*)alloc((size_t)N_NODES * 64 * 4);
    unsigned int* H1 = (unsigned int*)alloc((size_t)N_NODES * 64 * 4);

    prep_kernel<<<dim3((PREP_TOTAL + 255) / 256), dim3(256), 0, stream>>>(
        x, Xb, r0, w0, Wp0, r1, w1, Wp1, r2, w2, Wp2, cnt);
    rank_kernel<<<dim3((N_EDGES + 255) / 256), dim3(256), 0, stream>>>(ei, et, cnt, rank, N_EDGES);
    scanA_kernel<<<dim3((SCAN_T + 255) / 256), dim3(256), 0, stream>>>(cnt, tsum);
    scanB_kernel<<<dim3(1), dim3(1024), 0, stream>>>(tsum, toff);
    scanC_kernel<<<dim3((SCAN_T + 255) / 256), dim3(256), 0, stream>>>(cnt, toff, rs8);
    place_kernel<<<dim3((N_EDGES + 255) / 256), dim3(256), 0, stream>>>(ei, et, rank, rs8,
                                                                        csr_src, N_EDGES);

    layer_kernel<128, true ><<<dim3(NT32), dim3(1024), 0, stream>>>(
        Xb, rs8, csr_src, Wp0, b0, (void*)H0);
    layer_kernel<128, true ><<<dim3(NT32), dim3(1024), 0, stream>>>(
        H0, rs8, csr_src, Wp1, b1, (void*)H1);
    layer_kernel<16, false><<<dim3(NT32), dim3(1024), 0, stream>>>(
        H1, rs8, csr_src, Wp2, b2, d_out);
}